// Round 4
// baseline (548.902 us; speedup 1.0000x reference)
//
#include <hip/hip_runtime.h>
#include <math.h>

#define NPTS  16384
#define KNN   16
#define SEQV  8
#define NPART 16
#define PLEN  (NPTS / NPART)   // 1024
#define COLD  128              // per-partition self-sample size
#define BATCH 16
#define CAP   37               // 37 mod 32 = 5 (coprime) -> conflict-free appends

__device__ __forceinline__ unsigned umin_(unsigned a, unsigned b) { return a < b ? a : b; }
__device__ __forceinline__ unsigned umax_(unsigned a, unsigned b) { return a > b ? a : b; }

// merge one key into sorted ascending keys[16]
__device__ __forceinline__ void merge_one(unsigned keys[KNN], unsigned kk) {
    if (kk < keys[KNN - 1]) {
#pragma unroll
        for (int u = 0; u < KNN; ++u) {
            unsigned lo = umin_(kk, keys[u]);
            kk = umax_(kk, keys[u]);
            keys[u] = lo;
        }
    }
}

// ---------------------------------------------------------------------------
// K1: self-sampling partitioned kNN. Grid (64, NPART), 256 thr.
// Thread = (query i, partition p). Cold-chains first COLD candidates of its
// partition -> tau_p (>= partition 16th), then filter-scans the rest through
// an LDS append buffer. Exact per-partition top-16 -> part[p][i][16].
// key = (d2 bits & 0xFFFFC000) | j  (j < 2^14).
// ---------------------------------------------------------------------------
__global__ __launch_bounds__(256, 4) void knn_kernel(
    const float* __restrict__ pc, unsigned* __restrict__ part)
{
    __shared__ unsigned sbuf[256 * CAP];
    unsigned* buf = &sbuf[threadIdx.x * CAP];

    const int i = blockIdx.x * 256 + threadIdx.x;
    const int p = blockIdx.y;

    const float qx = pc[3 * i + 0];
    const float qy = pc[3 * i + 1];
    const float qz = pc[3 * i + 2];

    unsigned keys[KNN];
#pragma unroll
    for (int t = 0; t < KNN; ++t) keys[t] = 0xFFFFFFFFu;

    const int jbeg = p * PLEN;

    // ---- cold phase: exact top-16 of first COLD candidates (chain) ----
#pragma unroll 1
    for (int j = jbeg; j < jbeg + COLD; j += BATCH) {
        const int ju = __builtin_amdgcn_readfirstlane(j);
        const float* cb = pc + 3 * (size_t)ju;     // uniform -> s_load bursts
        unsigned kb[BATCH];
#pragma unroll
        for (int q = 0; q < BATCH; ++q) {
            float dx = qx - cb[3 * q + 0];
            float dy = qy - cb[3 * q + 1];
            float dz = qz - cb[3 * q + 2];
            float d2 = fmaf(dx, dx, fmaf(dy, dy, dz * dz));
            kb[q] = (__float_as_uint(d2) & 0xFFFFC000u) | (unsigned)(j + q);
        }
#pragma unroll
        for (int q = 0; q < BATCH; ++q) merge_one(keys, kb[q]);
    }

    unsigned tau = keys[KNN - 1];   // >= partition's true 16th key
    int cnt = 0;

    // ---- filtered phase ----
#pragma unroll 1
    for (int j = jbeg + COLD; j < jbeg + PLEN; j += BATCH) {
        const int ju = __builtin_amdgcn_readfirstlane(j);
        const float* cb = pc + 3 * (size_t)ju;
#pragma unroll
        for (int q = 0; q < BATCH; ++q) {
            float dx = qx - cb[3 * q + 0];
            float dy = qy - cb[3 * q + 1];
            float dz = qz - cb[3 * q + 2];
            float d2 = fmaf(dx, dx, fmaf(dy, dy, dz * dz));
            unsigned key = (__float_as_uint(d2) & 0xFFFFC000u) | (unsigned)(j + q);
            buf[cnt] = key;                 // unconditional write (slot reused)
            cnt += (key <= tau) ? 1 : 0;    // predicated advance
        }
        // headroom: enter batch with cnt <= CAP-BATCH-1 = 20; writes reach
        // index <= 20+15 = 35 <= CAP-1.
        if (cnt >= CAP - BATCH) {
#pragma unroll 1
            for (int t = 0; t < cnt; ++t) merge_one(keys, buf[t]);
            cnt = 0;
            tau = umin_(tau, keys[KNN - 1]);   // tightened, still exact
        }
    }

#pragma unroll 1
    for (int t = 0; t < cnt; ++t) merge_one(keys, buf[t]);

    unsigned* dst = part + ((size_t)p * NPTS + i) * KNN;
#pragma unroll
    for (int t = 0; t < KNN; ++t) dst[t] = keys[t];
}

// ---------------------------------------------------------------------------
// K2: merge partitions + radius filter + loss + finalize. Grid (64), 1024 thr.
// Wave-group g==0 merges the 16 lists for its 256 queries -> ids in LDS and
// accumulates the weight sum. All threads then gather: thread (q,g) handles
// s = g and g+4. Block partial -> atomicAdd; last block (ticket) finalizes.
// accum[0]=loss sum, accum[1]=wsum, accum[2]=ticket (zeroed by memset).
// ---------------------------------------------------------------------------
__global__ __launch_bounds__(1024) void loss_kernel(
    const float* __restrict__ flow, const float* __restrict__ w,
    const unsigned* __restrict__ part, float* __restrict__ accum,
    float* __restrict__ out)
{
    __shared__ int   sIds[256 * 17];   // stride 17 -> conflict-free
    __shared__ float sred[16];

    const int tid = threadIdx.x;
    const int q   = tid & 255;
    const int g   = tid >> 8;          // 0..3
    const int i   = blockIdx.x * 256 + q;

    if (g == 0) {
        unsigned keys[KNN];
#pragma unroll
        for (int t = 0; t < KNN; ++t) keys[t] = 0xFFFFFFFFu;
#pragma unroll 1
        for (int p = 0; p < NPART; ++p) {
            const unsigned* src = part + ((size_t)p * NPTS + i) * KNN;
#pragma unroll
            for (int t = 0; t < KNN; ++t) merge_one(keys, src[t]);
        }
        const int id0 = (int)(keys[0] & 0x3FFFu);   // nearest (self)
#pragma unroll
        for (int t = 0; t < KNN; ++t) {
            float d2t = __uint_as_float(keys[t] & 0xFFFFC000u);
            int   j   = (int)(keys[t] & 0x3FFFu);
            sIds[q * 17 + t] = (d2t > 1.0f) ? id0 : j;
        }
        float wi = w[i];
#pragma unroll
        for (int off = 32; off > 0; off >>= 1) wi += __shfl_down(wi, off);
        if ((tid & 63) == 0) atomicAdd(&accum[1], wi);
    }
    __syncthreads();

    int ids[KNN];
#pragma unroll
    for (int t = 0; t < KNN; ++t) ids[t] = sIds[q * 17 + t];

    float sum = 0.0f;
#pragma unroll
    for (int h = 0; h < 2; ++h) {
        const int s = g + 4 * h;
        const float* fs = flow + (size_t)s * NPTS * 3;
        const float fx = fs[3 * i + 0];
        const float fy = fs[3 * i + 1];
        const float fz = fs[3 * i + 2];
#pragma unroll
        for (int t = 0; t < KNN; ++t) {
            int j = ids[t];
            float dx = fx - fs[3 * j + 0];
            float dy = fy - fs[3 * j + 1];
            float dz = fz - fs[3 * j + 2];
            float sq = fmaf(dx, dx, fmaf(dy, dy, dz * dz));
            sum += (sq > 0.0f) ? sqrtf(sq) : 0.0f;
        }
    }

    float contrib = w[i] * sum;
#pragma unroll
    for (int off = 32; off > 0; off >>= 1) contrib += __shfl_down(contrib, off);
    if ((tid & 63) == 0) sred[tid >> 6] = contrib;
    __syncthreads();

    if (tid == 0) {
        float c = 0.0f;
#pragma unroll
        for (int t = 0; t < 16; ++t) c += sred[t];
        atomicAdd(&accum[0], c);
        __threadfence();
        unsigned ticket = atomicAdd((unsigned*)&accum[2], 1u);
        if (ticket == gridDim.x - 1) {
            float a  = atomicAdd(&accum[0], 0.0f);   // coherent L2 read
            float ws = atomicAdd(&accum[1], 0.0f);
            float v  = a / (float)(KNN * SEQV);
            out[0] = (ws > 0.0f) ? (v / ws) : v;
        }
    }
}

extern "C" void kernel_launch(void* const* d_in, const int* in_sizes, int n_in,
                              void* d_out, int out_size, void* d_ws, size_t ws_size,
                              hipStream_t stream)
{
    const float* pc   = (const float*)d_in[0];   // (1, N, 3)
    const float* flow = (const float*)d_in[1];   // (SEQ, N, 3)
    const float* wts  = (const float*)d_in[2];   // (N,)
    float* out = (float*)d_out;

    float*    accum = (float*)d_ws;
    unsigned* part  = (unsigned*)((char*)d_ws + 256);   // 16 MB (fits: R3 ran same)

    hipMemsetAsync(d_ws, 0, 64, stream);

    knn_kernel<<<dim3(NPTS / 256, NPART), 256, 0, stream>>>(pc, part);
    loss_kernel<<<NPTS / 256, 1024, 0, stream>>>(flow, wts, part, accum, out);
}